// Round 5
// baseline (376.843 us; speedup 1.0000x reference)
//
#include <hip/hip_runtime.h>
#include <hip/hip_fp16.h>

#define S_LEN 4096
#define B_N   32
#define H_N   512
#define BH    (B_N * H_N)        // 16384
#define CROWS 64                 // s-rows per fused block
#define NCH   (S_LEN / CROWS)    // 64 chunks per b

typedef __attribute__((ext_vector_type(8))) short bf16x8;
typedef __attribute__((ext_vector_type(4))) float f32x4;
typedef __attribute__((ext_vector_type(4))) unsigned short us4;

__device__ __forceinline__ unsigned short f2bf(float x) {
    union { float f; unsigned u; } c; c.f = x;
    unsigned r = c.u + 0x7fffu + ((c.u >> 16) & 1u);   // RNE
    return (unsigned short)(r >> 16);
}

// ---------------- K0: Wk fp32 -> bf16 ----------------
__global__ __launch_bounds__(256) void wkconv_kernel(const float* __restrict__ Wk,
                                                     unsigned short* __restrict__ Wb) {
    size_t i = (size_t)(blockIdx.x * 256 + threadIdx.x) * 8;
    float4 v0 = *(const float4*)(Wk + i);
    float4 v1 = *(const float4*)(Wk + i + 4);
    us4 a = {f2bf(v0.x), f2bf(v0.y), f2bf(v0.z), f2bf(v0.w)};
    us4 b = {f2bf(v1.x), f2bf(v1.y), f2bf(v1.z), f2bf(v1.w)};
    *(us4*)(Wb + i)     = a;
    *(us4*)(Wb + i + 4) = b;
}

// ---------------- K1: hsum[b,h] = sum_s hs[s,b,h] ----------------
__global__ __launch_bounds__(256) void hsum_kernel(const float* __restrict__ hs,
                                                   float* __restrict__ hsum) {
    int col = (blockIdx.x * 256 + threadIdx.x) * 4;
    size_t s0 = (size_t)blockIdx.y * 128;
    float4 acc = {0.f, 0.f, 0.f, 0.f};
    #pragma unroll 8
    for (int i = 0; i < 128; ++i) {
        float4 v = *(const float4*)(hs + (s0 + i) * BH + col);
        acc.x += v.x; acc.y += v.y; acc.z += v.z; acc.w += v.w;
    }
    atomicAdd(&hsum[col],     acc.x);
    atomicAdd(&hsum[col + 1], acc.y);
    atomicAdd(&hsum[col + 2], acc.z);
    atomicAdd(&hsum[col + 3], acc.w);
}

// ---------------- K2: q[b,h] ----------------
__global__ __launch_bounds__(256) void q_kernel(const float* __restrict__ hsum,
                                                const float* __restrict__ Wq,
                                                const float* __restrict__ bq,
                                                float* __restrict__ q) {
    int b = blockIdx.x, t = threadIdx.x;
    __shared__ float hrow[H_N];
    hrow[t]       = hsum[b * H_N + t]       * (1.f / S_LEN);
    hrow[t + 256] = hsum[b * H_N + t + 256] * (1.f / S_LEN);
    __syncthreads();
    for (int h = t; h < H_N; h += 256) {
        const float* wrow = Wq + (size_t)h * H_N;
        float acc = 0.f;
        #pragma unroll 8
        for (int k = 0; k < H_N; ++k) acc = fmaf(hrow[k], wrow[k], acc);
        q[b * H_N + h] = acc + bq[h];
    }
}

// ---------------- K3: fused key GEMM + tanh + scores + softmax + PV partials ----------------
// 512 thr = 8 waves (2 wm x 4 wn). 64 rows x 512 cols per block.
// A tile 64x512 bf16 in LDS (swizzled, staged once). B just-in-time from L2.
// acc[2][8] (64 AGPR) -> combined regs <= 128 -> 4 waves/SIMD, 2 blocks/CU.
__global__ __launch_bounds__(512, 4) void fused_kernel(
    const float* __restrict__ hs, const unsigned short* __restrict__ Wb,
    const float* __restrict__ bk, const float* __restrict__ qv,
    const int* __restrict__ lengths,
    float* __restrict__ pm, float* __restrict__ pl, float* __restrict__ po)
{
    int blk = blockIdx.x;
    int b = blk & 31;
    int chunk = blk >> 5;
    int s0 = chunk * CROWS;
    int t = threadIdx.x;
    int lane = t & 63, wv = t >> 6;
    int l15 = lane & 15, lg = lane >> 4;
    int wm = wv >> 2, wn = wv & 3;

    __shared__ __align__(16) unsigned short A_s[CROWS * H_N]; // 64 KB; opart aliases here later
    __shared__ float q_s[H_N];
    __shared__ float bk_s[H_N];
    __shared__ float scp[4][CROWS];
    __shared__ float score_s[CROWS];
    __shared__ float p_s[CROWS];

    int len = lengths[b];
    if (t < 256) { q_s[t] = qv[b * H_N + t]; q_s[t + 256] = qv[b * H_N + t + 256];
                   bk_s[t] = bk[t]; bk_s[t + 256] = bk[t + 256]; }
    else         { q_s[t - 256 + 0] = q_s[t - 256 + 0]; }   // no-op for other half
    // (both halves written by t<256 branch; 512-thread redundant path avoided)

    // ---- stage A: 64 rows x 512 cols fp32 -> bf16, swizzle byte ^= (row&7)<<4 ----
    const float* hb = hs + ((size_t)s0 * B_N + b) * H_N;   // row stride BH floats
    int kq  = t & 127;          // float4 index within row
    int r0l = t >> 7;           // 0..3
    #pragma unroll 8
    for (int j = 0; j < 16; ++j) {
        int row = r0l + 4 * j;
        float4 v = *(const float4*)(hb + (size_t)row * BH + kq * 4);
        us4 u = {f2bf(v.x), f2bf(v.y), f2bf(v.z), f2bf(v.w)};
        *(us4*)((char*)A_s + row * 1024 + ((kq * 8) ^ ((row & 7) << 4))) = u;
    }
    __syncthreads();

    // ---- K-loop: 16 steps of k32, B loaded just-in-time (TLP hides L2) ----
    const unsigned short* wbL = Wb + (size_t)(wn * 128 + l15) * H_N + lg * 8;
    const char* Ab = (const char*)A_s + (wm * 32 + l15) * 1024;
    int axor = (l15 & 7) << 4;

    f32x4 acc[2][8];
    #pragma unroll
    for (int m = 0; m < 2; ++m)
        #pragma unroll
        for (int n = 0; n < 8; ++n) acc[m][n] = (f32x4){0.f, 0.f, 0.f, 0.f};

    #pragma unroll
    for (int ks = 0; ks < 16; ++ks) {
        bf16x8 b0 = *(const bf16x8*)(wbL + 0 * 16 * H_N + ks * 32);
        bf16x8 b1 = *(const bf16x8*)(wbL + 1 * 16 * H_N + ks * 32);
        bf16x8 b2 = *(const bf16x8*)(wbL + 2 * 16 * H_N + ks * 32);
        bf16x8 b3 = *(const bf16x8*)(wbL + 3 * 16 * H_N + ks * 32);
        bf16x8 b4 = *(const bf16x8*)(wbL + 4 * 16 * H_N + ks * 32);
        bf16x8 b5 = *(const bf16x8*)(wbL + 5 * 16 * H_N + ks * 32);
        bf16x8 b6 = *(const bf16x8*)(wbL + 6 * 16 * H_N + ks * 32);
        bf16x8 b7 = *(const bf16x8*)(wbL + 7 * 16 * H_N + ks * 32);
        int off = (ks * 64 + lg * 16) ^ axor;
        bf16x8 a0 = *(const bf16x8*)(Ab + off);
        bf16x8 a1 = *(const bf16x8*)(Ab + 16 * 1024 + off);
        __builtin_amdgcn_s_setprio(1);
        acc[0][0] = __builtin_amdgcn_mfma_f32_16x16x32_bf16(a0, b0, acc[0][0], 0, 0, 0);
        acc[1][0] = __builtin_amdgcn_mfma_f32_16x16x32_bf16(a1, b0, acc[1][0], 0, 0, 0);
        acc[0][1] = __builtin_amdgcn_mfma_f32_16x16x32_bf16(a0, b1, acc[0][1], 0, 0, 0);
        acc[1][1] = __builtin_amdgcn_mfma_f32_16x16x32_bf16(a1, b1, acc[1][1], 0, 0, 0);
        acc[0][2] = __builtin_amdgcn_mfma_f32_16x16x32_bf16(a0, b2, acc[0][2], 0, 0, 0);
        acc[1][2] = __builtin_amdgcn_mfma_f32_16x16x32_bf16(a1, b2, acc[1][2], 0, 0, 0);
        acc[0][3] = __builtin_amdgcn_mfma_f32_16x16x32_bf16(a0, b3, acc[0][3], 0, 0, 0);
        acc[1][3] = __builtin_amdgcn_mfma_f32_16x16x32_bf16(a1, b3, acc[1][3], 0, 0, 0);
        acc[0][4] = __builtin_amdgcn_mfma_f32_16x16x32_bf16(a0, b4, acc[0][4], 0, 0, 0);
        acc[1][4] = __builtin_amdgcn_mfma_f32_16x16x32_bf16(a1, b4, acc[1][4], 0, 0, 0);
        acc[0][5] = __builtin_amdgcn_mfma_f32_16x16x32_bf16(a0, b5, acc[0][5], 0, 0, 0);
        acc[1][5] = __builtin_amdgcn_mfma_f32_16x16x32_bf16(a1, b5, acc[1][5], 0, 0, 0);
        acc[0][6] = __builtin_amdgcn_mfma_f32_16x16x32_bf16(a0, b6, acc[0][6], 0, 0, 0);
        acc[1][6] = __builtin_amdgcn_mfma_f32_16x16x32_bf16(a1, b6, acc[1][6], 0, 0, 0);
        acc[0][7] = __builtin_amdgcn_mfma_f32_16x16x32_bf16(a0, b7, acc[0][7], 0, 0, 0);
        acc[1][7] = __builtin_amdgcn_mfma_f32_16x16x32_bf16(a1, b7, acc[1][7], 0, 0, 0);
        __builtin_amdgcn_s_setprio(0);
    }

    // ---- epilogue: bias + tanh (in place) + score partials ----
    // C/D: lane holds D[row = wm*32 + m*16 + lg*4 + i][col = wn*128 + n*16 + l15]
    float sp[2][4] = {{0,0,0,0},{0,0,0,0}};
    #pragma unroll
    for (int m = 0; m < 2; ++m)
        #pragma unroll
        for (int n = 0; n < 8; ++n) {
            int c = wn * 128 + n * 16 + l15;
            float bkv = bk_s[c], qc = q_s[c];
            #pragma unroll
            for (int i = 0; i < 4; ++i) {
                float z = acc[m][n][i] + bkv;
                float e = __expf(2.f * z);
                float kv = 1.f - 2.f / (e + 1.f);     // tanh
                acc[m][n][i] = kv;                    // key kept in regs
                sp[m][i] = fmaf(kv, qc, sp[m][i]);
            }
        }
    #pragma unroll
    for (int m = 0; m < 2; ++m)
        #pragma unroll
        for (int i = 0; i < 4; ++i) {
            float v = sp[m][i];
            v += __shfl_xor(v, 1); v += __shfl_xor(v, 2);
            v += __shfl_xor(v, 4); v += __shfl_xor(v, 8);
            if (l15 == 0) scp[wn][wm * 32 + m * 16 + lg * 4 + i] = v;
        }
    __syncthreads();

    // ---- softmax over the 64 rows ----
    if (t < CROWS) {
        float sc = scp[0][t] + scp[1][t] + scp[2][t] + scp[3][t];
        if (s0 + t >= len) sc -= 10000.f;
        score_s[t] = sc;
    }
    __syncthreads();
    float mx = -1e30f;
    #pragma unroll 8
    for (int r = 0; r < CROWS; ++r) mx = fmaxf(mx, score_s[r]);
    if (t < CROWS) p_s[t] = __expf(score_s[t] - mx);
    __syncthreads();

    // ---- PV from register-resident key; partials into LDS aliased over A_s ----
    float* opart = (float*)A_s;               // [8][H_N] = 16 KB, A_s no longer read
    float o8[8] = {0,0,0,0,0,0,0,0};
    #pragma unroll
    for (int m = 0; m < 2; ++m)
        #pragma unroll
        for (int i = 0; i < 4; ++i) {
            float p = p_s[wm * 32 + m * 16 + lg * 4 + i];
            #pragma unroll
            for (int n = 0; n < 8; ++n) o8[n] = fmaf(p, acc[m][n][i], o8[n]);
        }
    int slice = wm * 4 + lg;
    #pragma unroll
    for (int n = 0; n < 8; ++n) opart[slice * H_N + wn * 128 + n * 16 + l15] = o8[n];
    __syncthreads();

    if (t < H_N) {
        float o = 0.f;
        #pragma unroll
        for (int s = 0; s < 8; ++s) o += opart[s * H_N + t];
        po[((size_t)b * NCH + chunk) * H_N + t] = o;
    }
    if (t == 0) {
        float l = 0.f;
        #pragma unroll 8
        for (int r = 0; r < CROWS; ++r) l += p_s[r];
        pm[b * NCH + chunk] = mx;
        pl[b * NCH + chunk] = l;
    }
}

// ---------------- K4: combine chunk partials ----------------
__global__ __launch_bounds__(256) void combine_kernel(
    const float* __restrict__ pm, const float* __restrict__ pl,
    const float* __restrict__ po, float* __restrict__ out)
{
    int b = blockIdx.x, t = threadIdx.x;
    float M = -1e30f;
    for (int c = 0; c < NCH; ++c) M = fmaxf(M, pm[b * NCH + c]);
    float den = 0.f, n0 = 0.f, n1 = 0.f;
    for (int c = 0; c < NCH; ++c) {
        float w = __expf(pm[b * NCH + c] - M);
        den = fmaf(w, pl[b * NCH + c], den);
        const float* op = po + (size_t)(b * NCH + c) * H_N;
        n0 = fmaf(w, op[t], n0);
        n1 = fmaf(w, op[t + 256], n1);
    }
    out[b * H_N + t]       = n0 / den;
    out[b * H_N + t + 256] = n1 / den;
}

extern "C" void kernel_launch(void* const* d_in, const int* in_sizes, int n_in,
                              void* d_out, int out_size, void* d_ws, size_t ws_size,
                              hipStream_t stream) {
    const float* hs      = (const float*)d_in[0];
    const float* Wq      = (const float*)d_in[1];
    const float* bq      = (const float*)d_in[2];
    const float* Wk      = (const float*)d_in[3];
    const float* bk      = (const float*)d_in[4];
    const int*   lengths = (const int*)d_in[5];
    float* out = (float*)d_out;

    float* ws   = (float*)d_ws;
    float* hsum = ws;                              // 16384
    float* qv   = hsum + BH;                       // 16384
    float* pm   = qv + BH;                         // 2048
    float* pl   = pm + B_N * NCH;                  // 2048
    float* po   = pl + B_N * NCH;                  // 32*64*512 = 1048576
    unsigned short* Wb = (unsigned short*)(po + (size_t)B_N * NCH * H_N); // 512 KB

    hipMemsetAsync(hsum, 0, BH * sizeof(float), stream);
    hipLaunchKernelGGL(wkconv_kernel, dim3(H_N * H_N / (8 * 256)), dim3(256), 0, stream, Wk, Wb);
    hipLaunchKernelGGL(hsum_kernel, dim3(BH / 1024, S_LEN / 128), dim3(256), 0, stream, hs, hsum);
    hipLaunchKernelGGL(q_kernel, dim3(B_N), dim3(256), 0, stream, hsum, Wq, bq, qv);
    hipLaunchKernelGGL(fused_kernel, dim3(B_N * NCH), dim3(512), 0, stream,
                       hs, Wb, bk, qv, lengths, pm, pl, po);
    hipLaunchKernelGGL(combine_kernel, dim3(B_N), dim3(256), 0, stream, pm, pl, po, out);
}

// Round 6
// 222.099 us; speedup vs baseline: 1.6967x; 1.6967x over previous
//
#include <hip/hip_runtime.h>
#include <hip/hip_fp16.h>

#define S_LEN 4096
#define B_N   32
#define H_N   512
#define BH    (B_N * H_N)        // 16384
#define CROWS 64                 // s-rows per fused block
#define NCH   (S_LEN / CROWS)    // 64 chunks per b

typedef __attribute__((ext_vector_type(8))) short bf16x8;
typedef __attribute__((ext_vector_type(4))) float f32x4;
typedef __attribute__((ext_vector_type(4))) unsigned short us4;

__device__ __forceinline__ unsigned short f2bf(float x) {
    union { float f; unsigned u; } c; c.f = x;
    unsigned r = c.u + 0x7fffu + ((c.u >> 16) & 1u);   // RNE
    return (unsigned short)(r >> 16);
}

// ---------------- K0: Wk fp32 -> bf16 in MFMA-FRAGMENT order ----------------
// WbF element index = ((wn*16 + ks)*8 + n)*512 + lane*8 + j
// maps to Wk[col][k] with col = wn*128 + n*16 + (lane&15), k = ks*32 + (lane>>4)*8 + j.
// A wave's B-load becomes base + lane*16B -> 1KB contiguous per instruction.
__global__ __launch_bounds__(256) void wkfrag_kernel(const float* __restrict__ Wk,
                                                     unsigned short* __restrict__ WbF) {
    int g = blockIdx.x * 256 + threadIdx.x;   // 0..32767 lane-slots
    int lane = g & 63;
    int n    = (g >> 6) & 7;
    int ks   = (g >> 9) & 15;
    int wn   = g >> 13;
    int col = wn * 128 + n * 16 + (lane & 15);
    int k   = ks * 32 + (lane >> 4) * 8;
    const float* src = Wk + (size_t)col * H_N + k;
    float4 v0 = *(const float4*)(src);
    float4 v1 = *(const float4*)(src + 4);
    us4 a = {f2bf(v0.x), f2bf(v0.y), f2bf(v0.z), f2bf(v0.w)};
    us4 b = {f2bf(v1.x), f2bf(v1.y), f2bf(v1.z), f2bf(v1.w)};
    *(us4*)(WbF + (size_t)g * 8)     = a;
    *(us4*)(WbF + (size_t)g * 8 + 4) = b;
}

// ---------------- K1: hsum[b,h] = sum_s hs[s,b,h] ----------------
__global__ __launch_bounds__(256) void hsum_kernel(const float* __restrict__ hs,
                                                   float* __restrict__ hsum) {
    int col = (blockIdx.x * 256 + threadIdx.x) * 4;
    size_t s0 = (size_t)blockIdx.y * 128;
    float4 acc = {0.f, 0.f, 0.f, 0.f};
    #pragma unroll 8
    for (int i = 0; i < 128; ++i) {
        float4 v = *(const float4*)(hs + (s0 + i) * BH + col);
        acc.x += v.x; acc.y += v.y; acc.z += v.z; acc.w += v.w;
    }
    atomicAdd(&hsum[col],     acc.x);
    atomicAdd(&hsum[col + 1], acc.y);
    atomicAdd(&hsum[col + 2], acc.z);
    atomicAdd(&hsum[col + 3], acc.w);
}

// ---------------- K2: q[b,h] ----------------
__global__ __launch_bounds__(256) void q_kernel(const float* __restrict__ hsum,
                                                const float* __restrict__ Wq,
                                                const float* __restrict__ bq,
                                                float* __restrict__ q) {
    int b = blockIdx.x, t = threadIdx.x;
    __shared__ float hrow[H_N];
    hrow[t]       = hsum[b * H_N + t]       * (1.f / S_LEN);
    hrow[t + 256] = hsum[b * H_N + t + 256] * (1.f / S_LEN);
    __syncthreads();
    for (int h = t; h < H_N; h += 256) {
        const float* wrow = Wq + (size_t)h * H_N;
        float acc = 0.f;
        #pragma unroll 8
        for (int k = 0; k < H_N; ++k) acc = fmaf(hrow[k], wrow[k], acc);
        q[b * H_N + h] = acc + bq[h];
    }
}

// ---------------- K3: fused key GEMM + tanh + scores + softmax + PV partials ----------------
// 512 thr = 8 waves (2 wm x 4 wn), 64 rows x 512 cols per block.
// Fully-masked chunks (s0 >= len) early-exit: exp(score-10000-M) == 0 in fp32,
// identical to reference. B loads coalesced via fragment-ordered WbF.
__global__ __launch_bounds__(512, 4) void fused_kernel(
    const float* __restrict__ hs, const unsigned short* __restrict__ WbF,
    const float* __restrict__ bk, const float* __restrict__ qv,
    const int* __restrict__ lengths,
    float* __restrict__ pm, float* __restrict__ pl, float* __restrict__ po)
{
    int blk = blockIdx.x;
    int b = blk & 31;
    int chunk = blk >> 5;
    int s0 = chunk * CROWS;
    int t = threadIdx.x;

    int len = lengths[b];
    if (s0 >= len) {                       // fully masked: contributes exactly 0
        po[((size_t)b * NCH + chunk) * H_N + t] = 0.f;
        if (t == 0) { pm[b * NCH + chunk] = -1e30f; pl[b * NCH + chunk] = 0.f; }
        return;
    }

    int lane = t & 63, wv = t >> 6;
    int l15 = lane & 15, lg = lane >> 4;
    int wm = wv >> 2, wn = wv & 3;

    __shared__ __align__(16) unsigned short A_s[CROWS * H_N]; // 64 KB; opart aliases later
    __shared__ float q_s[H_N];
    __shared__ float bk_s[H_N];
    __shared__ float scp[4][CROWS];
    __shared__ float score_s[CROWS];
    __shared__ float p_s[CROWS];

    q_s[t]  = qv[b * H_N + t];    // 512 threads cover 512 entries
    bk_s[t] = bk[t];

    // ---- stage A: 64 rows x 512 cols fp32 -> bf16, swizzle byte ^= (row&7)<<4 ----
    const float* hb = hs + ((size_t)s0 * B_N + b) * H_N;   // row stride BH floats
    int kq  = t & 127;
    int r0l = t >> 7;
    #pragma unroll 8
    for (int j = 0; j < 16; ++j) {
        int row = r0l + 4 * j;
        float4 v = *(const float4*)(hb + (size_t)row * BH + kq * 4);
        us4 u = {f2bf(v.x), f2bf(v.y), f2bf(v.z), f2bf(v.w)};
        *(us4*)((char*)A_s + row * 1024 + ((kq * 8) ^ ((row & 7) << 4))) = u;
    }
    __syncthreads();

    // ---- K-loop: 16 steps of k32; B from fragment-ordered WbF (coalesced) ----
    const unsigned short* wbF = WbF + (size_t)wn * 65536 + lane * 8;  // wn*16*8*512
    const char* Ab = (const char*)A_s + (wm * 32 + l15) * 1024;
    int axor = (l15 & 7) << 4;

    f32x4 acc[2][8];
    #pragma unroll
    for (int m = 0; m < 2; ++m)
        #pragma unroll
        for (int n = 0; n < 8; ++n) acc[m][n] = (f32x4){0.f, 0.f, 0.f, 0.f};

    #pragma unroll
    for (int ks = 0; ks < 16; ++ks) {
        const unsigned short* wk = wbF + ks * 4096;   // ks*8*512
        bf16x8 b0 = *(const bf16x8*)(wk + 0 * 512);
        bf16x8 b1 = *(const bf16x8*)(wk + 1 * 512);
        bf16x8 b2 = *(const bf16x8*)(wk + 2 * 512);
        bf16x8 b3 = *(const bf16x8*)(wk + 3 * 512);
        bf16x8 b4 = *(const bf16x8*)(wk + 4 * 512);
        bf16x8 b5 = *(const bf16x8*)(wk + 5 * 512);
        bf16x8 b6 = *(const bf16x8*)(wk + 6 * 512);
        bf16x8 b7 = *(const bf16x8*)(wk + 7 * 512);
        int off = (ks * 64 + lg * 16) ^ axor;
        bf16x8 a0 = *(const bf16x8*)(Ab + off);
        bf16x8 a1 = *(const bf16x8*)(Ab + 16 * 1024 + off);
        __builtin_amdgcn_s_setprio(1);
        acc[0][0] = __builtin_amdgcn_mfma_f32_16x16x32_bf16(a0, b0, acc[0][0], 0, 0, 0);
        acc[1][0] = __builtin_amdgcn_mfma_f32_16x16x32_bf16(a1, b0, acc[1][0], 0, 0, 0);
        acc[0][1] = __builtin_amdgcn_mfma_f32_16x16x32_bf16(a0, b1, acc[0][1], 0, 0, 0);
        acc[1][1] = __builtin_amdgcn_mfma_f32_16x16x32_bf16(a1, b1, acc[1][1], 0, 0, 0);
        acc[0][2] = __builtin_amdgcn_mfma_f32_16x16x32_bf16(a0, b2, acc[0][2], 0, 0, 0);
        acc[1][2] = __builtin_amdgcn_mfma_f32_16x16x32_bf16(a1, b2, acc[1][2], 0, 0, 0);
        acc[0][3] = __builtin_amdgcn_mfma_f32_16x16x32_bf16(a0, b3, acc[0][3], 0, 0, 0);
        acc[1][3] = __builtin_amdgcn_mfma_f32_16x16x32_bf16(a1, b3, acc[1][3], 0, 0, 0);
        acc[0][4] = __builtin_amdgcn_mfma_f32_16x16x32_bf16(a0, b4, acc[0][4], 0, 0, 0);
        acc[1][4] = __builtin_amdgcn_mfma_f32_16x16x32_bf16(a1, b4, acc[1][4], 0, 0, 0);
        acc[0][5] = __builtin_amdgcn_mfma_f32_16x16x32_bf16(a0, b5, acc[0][5], 0, 0, 0);
        acc[1][5] = __builtin_amdgcn_mfma_f32_16x16x32_bf16(a1, b5, acc[1][5], 0, 0, 0);
        acc[0][6] = __builtin_amdgcn_mfma_f32_16x16x32_bf16(a0, b6, acc[0][6], 0, 0, 0);
        acc[1][6] = __builtin_amdgcn_mfma_f32_16x16x32_bf16(a1, b6, acc[1][6], 0, 0, 0);
        acc[0][7] = __builtin_amdgcn_mfma_f32_16x16x32_bf16(a0, b7, acc[0][7], 0, 0, 0);
        acc[1][7] = __builtin_amdgcn_mfma_f32_16x16x32_bf16(a1, b7, acc[1][7], 0, 0, 0);
        __builtin_amdgcn_s_setprio(0);
    }

    // ---- epilogue: bias + tanh (in place) + score partials ----
    // C/D: lane holds D[row = wm*32 + m*16 + lg*4 + i][col = wn*128 + n*16 + l15]
    float sp[2][4] = {{0,0,0,0},{0,0,0,0}};
    #pragma unroll
    for (int m = 0; m < 2; ++m)
        #pragma unroll
        for (int n = 0; n < 8; ++n) {
            int c = wn * 128 + n * 16 + l15;
            float bkv = bk_s[c], qc = q_s[c];
            #pragma unroll
            for (int i = 0; i < 4; ++i) {
                float z = acc[m][n][i] + bkv;
                float e = __expf(2.f * z);
                float kv = 1.f - 2.f / (e + 1.f);     // tanh
                acc[m][n][i] = kv;                    // key kept in regs
                sp[m][i] = fmaf(kv, qc, sp[m][i]);
            }
        }
    #pragma unroll
    for (int m = 0; m < 2; ++m)
        #pragma unroll
        for (int i = 0; i < 4; ++i) {
            float v = sp[m][i];
            v += __shfl_xor(v, 1); v += __shfl_xor(v, 2);
            v += __shfl_xor(v, 4); v += __shfl_xor(v, 8);
            if (l15 == 0) scp[wn][wm * 32 + m * 16 + lg * 4 + i] = v;
        }
    __syncthreads();

    // ---- softmax over the 64 rows ----
    if (t < CROWS) {
        float sc = scp[0][t] + scp[1][t] + scp[2][t] + scp[3][t];
        if (s0 + t >= len) sc -= 10000.f;
        score_s[t] = sc;
    }
    __syncthreads();
    float mx = -1e30f;
    #pragma unroll 8
    for (int r = 0; r < CROWS; ++r) mx = fmaxf(mx, score_s[r]);
    if (t < CROWS) p_s[t] = __expf(score_s[t] - mx);
    __syncthreads();

    // ---- PV from register-resident key; partials into LDS aliased over A_s ----
    float* opart = (float*)A_s;               // [8][H_N] = 16 KB
    float o8[8] = {0,0,0,0,0,0,0,0};
    #pragma unroll
    for (int m = 0; m < 2; ++m)
        #pragma unroll
        for (int i = 0; i < 4; ++i) {
            float p = p_s[wm * 32 + m * 16 + lg * 4 + i];
            #pragma unroll
            for (int n = 0; n < 8; ++n) o8[n] = fmaf(p, acc[m][n][i], o8[n]);
        }
    int slice = wm * 4 + lg;
    #pragma unroll
    for (int n = 0; n < 8; ++n) opart[slice * H_N + wn * 128 + n * 16 + l15] = o8[n];
    __syncthreads();

    {
        float o = 0.f;
        #pragma unroll
        for (int s = 0; s < 8; ++s) o += opart[s * H_N + t];
        po[((size_t)b * NCH + chunk) * H_N + t] = o;
    }
    if (t == 0) {
        float l = 0.f;
        #pragma unroll 8
        for (int r = 0; r < CROWS; ++r) l += p_s[r];
        pm[b * NCH + chunk] = mx;
        pl[b * NCH + chunk] = l;
    }
}

// ---------------- K4: combine chunk partials ----------------
__global__ __launch_bounds__(256) void combine_kernel(
    const float* __restrict__ pm, const float* __restrict__ pl,
    const float* __restrict__ po, float* __restrict__ out)
{
    int b = blockIdx.x, t = threadIdx.x;
    float M = -1e30f;
    for (int c = 0; c < NCH; ++c) M = fmaxf(M, pm[b * NCH + c]);
    float den = 0.f, n0 = 0.f, n1 = 0.f;
    for (int c = 0; c < NCH; ++c) {
        float w = __expf(pm[b * NCH + c] - M);
        den = fmaf(w, pl[b * NCH + c], den);
        const float* op = po + (size_t)(b * NCH + c) * H_N;
        n0 = fmaf(w, op[t], n0);
        n1 = fmaf(w, op[t + 256], n1);
    }
    out[b * H_N + t]       = n0 / den;
    out[b * H_N + t + 256] = n1 / den;
}

extern "C" void kernel_launch(void* const* d_in, const int* in_sizes, int n_in,
                              void* d_out, int out_size, void* d_ws, size_t ws_size,
                              hipStream_t stream) {
    const float* hs      = (const float*)d_in[0];
    const float* Wq      = (const float*)d_in[1];
    const float* bq      = (const float*)d_in[2];
    const float* Wk      = (const float*)d_in[3];
    const float* bk      = (const float*)d_in[4];
    const int*   lengths = (const int*)d_in[5];
    float* out = (float*)d_out;

    float* ws   = (float*)d_ws;
    float* hsum = ws;                              // 16384
    float* qv   = hsum + BH;                       // 16384
    float* pm   = qv + BH;                         // 2048
    float* pl   = pm + B_N * NCH;                  // 2048
    float* po   = pl + B_N * NCH;                  // 32*64*512 = 1048576
    unsigned short* WbF = (unsigned short*)(po + (size_t)B_N * NCH * H_N); // 512 KB

    hipMemsetAsync(hsum, 0, BH * sizeof(float), stream);
    hipLaunchKernelGGL(wkfrag_kernel, dim3(128), dim3(256), 0, stream, Wk, WbF);
    hipLaunchKernelGGL(hsum_kernel, dim3(BH / 1024, S_LEN / 128), dim3(256), 0, stream, hs, hsum);
    hipLaunchKernelGGL(q_kernel, dim3(B_N), dim3(256), 0, stream, hsum, Wq, bq, qv);
    hipLaunchKernelGGL(fused_kernel, dim3(B_N * NCH), dim3(512), 0, stream,
                       hs, WbF, bk, qv, lengths, pm, pl, po);
    hipLaunchKernelGGL(combine_kernel, dim3(B_N), dim3(256), 0, stream, pm, pl, po, out);
}